// Round 8
// baseline (42.182 us; speedup 1.0000x reference)
//
#include <hip/hip_runtime.h>
#include <math.h>

#define D 40
#define NN 1024
#define BB 2

typedef __attribute__((ext_vector_type(8))) _Float16 f16x8;
typedef __attribute__((ext_vector_type(4))) float f32x4;

__device__ __forceinline__ unsigned int pk16(float a, float b) {
    return __builtin_bit_cast(unsigned int, __builtin_amdgcn_cvt_pkrtz(a, b));
}

// gelu = a - a/(exp2(a*(c1*a^2+c0))+1); 5 VALU + 2 trans
__device__ __forceinline__ float gelu_tanh(float a) {
    float u = a * a;
    float t1 = fmaf(0.10294366f, u, 2.3022083f);
    float e = __builtin_amdgcn_exp2f(a * t1);
    float r = __builtin_amdgcn_rcpf(e + 1.0f);
    return fmaf(-a, r, a);
}

// anti-remat pins: asm-defined values can't be rematerialized by the allocator
__device__ __forceinline__ void pinf(float& x) { asm volatile("" : "+v"(x)); }
__device__ __forceinline__ void pin4(float4& v) {
    asm volatile("" : "+v"(v.x), "+v"(v.y), "+v"(v.z), "+v"(v.w));
}
__device__ __forceinline__ void pin8(f16x8& v) {
    uint4 u = __builtin_bit_cast(uint4, v);
    asm volatile("" : "+v"(u.x), "+v"(u.y), "+v"(u.z), "+v"(u.w));
    v = __builtin_bit_cast(f16x8, u);
}

// build fp16x8 B-fragment: gelu(air + ajv) for 8 consecutive k
__device__ __forceinline__ f16x8 frag8(float4 a0, float4 a1, float4 x0, float4 x1) {
    float g0 = gelu_tanh(a0.x + x0.x);
    float g1 = gelu_tanh(a0.y + x0.y);
    float g2 = gelu_tanh(a0.z + x0.z);
    float g3 = gelu_tanh(a0.w + x0.w);
    float g4 = gelu_tanh(a1.x + x1.x);
    float g5 = gelu_tanh(a1.y + x1.y);
    float g6 = gelu_tanh(a1.z + x1.z);
    float g7 = gelu_tanh(a1.w + x1.w);
    return __builtin_bit_cast(f16x8,
        make_uint4(pk16(g0, g1), pk16(g2, g3), pk16(g4, g5), pk16(g6, g7)));
}

// ai = x @ W1[:D] + b1, aj = x @ W1[D:]; block 0 packs W2^T fp16 A-fragments
__global__ __launch_bounds__(64) void precompute_kernel(
    const float* __restrict__ x, const float* __restrict__ W1,
    const float* __restrict__ b1, const float* __restrict__ W2,
    float* __restrict__ ai, float* __restrict__ aj, uint4* __restrict__ w2fT) {
    int r = blockIdx.x;
    int t = threadIdx.x;
    __shared__ float xr[D];
    if (t < D) xr[t] = x[(size_t)r * D + t];
    __syncthreads();
    if (t < D) {
        float s1 = b1[t];
        float s2 = 0.0f;
#pragma unroll
        for (int k = 0; k < D; ++k) {
            float xv = xr[k];
            s1 = fmaf(xv, W1[k * D + t], s1);
            s2 = fmaf(xv, W1[(D + k) * D + t], s2);
        }
        ai[(size_t)r * D + t] = s1;
        aj[(size_t)r * D + t] = s2;
    }
    if (r == 0) {
        // A = W2^T: A[m=d, k] = W2[k][d]; lane: m = l&15, k = kt*32 + (l>>4)*8 + e
        const int lr = t & 15, lg = t >> 4;
#pragma unroll
        for (int mt = 0; mt < 3; ++mt)
#pragma unroll
            for (int kt = 0; kt < 2; ++kt) {
                unsigned int u[4];
#pragma unroll
                for (int pe = 0; pe < 4; ++pe) {
                    int k0 = kt * 32 + lg * 8 + pe * 2;
                    int dd = mt * 16 + lr;
                    float v0 = (k0 < D && dd < D) ? W2[k0 * D + dd] : 0.0f;
                    float v1 = (k0 + 1 < D && dd < D) ? W2[(k0 + 1) * D + dd] : 0.0f;
                    u[pe] = pk16(v0, v1);
                }
                w2fT[(mt * 2 + kt) * 64 + t] = make_uint4(u[0], u[1], u[2], u[3]);
            }
    }
}

__global__ __launch_bounds__(256)
__attribute__((amdgpu_waves_per_eu(2, 4)))
void pair_kernel(
    const float* __restrict__ ai_g, const float* __restrict__ aj_g,
    const uint4* __restrict__ w2fT, const float* __restrict__ b2,
    float* __restrict__ out) {
    __shared__ float mbuf[224];               // 4 waves x 56 (only LDS in kernel)

    const int t = threadIdx.x;
    const int bid = blockIdx.x;
    const int bb = bid & 1;
    const int i = NN - 1 - (bid >> 1);        // big rows first
    const int w = t >> 6;
    const int l = t & 63;
    const int lr = l & 15;
    const int lg = l >> 4;

    // W2^T A-fragments (6 x 16B from L2), pinned resident
    f16x8 w2t[3][2];
#pragma unroll
    for (int mt = 0; mt < 3; ++mt)
#pragma unroll
        for (int kt = 0; kt < 2; ++kt) {
            w2t[mt][kt] = __builtin_bit_cast(f16x8, w2fT[(mt * 2 + kt) * 64 + l]);
            pin8(w2t[mt][kt]);
        }

    // bias for d = mt*16 + lg*4 + r (0 for d >= 40), pinned
    float bv2[3][4];
#pragma unroll
    for (int mt = 0; mt < 3; ++mt)
#pragma unroll
        for (int r = 0; r < 4; ++r) {
            int d = mt * 16 + lg * 4 + r;
            bv2[mt][r] = (d < D) ? b2[d] : 0.0f;
            pinf(bv2[mt][r]);
        }

    // ai fragment for this lane's k-slots: k = kt*32 + lg*8 + e, pinned
    const float* air_p = ai_g + ((size_t)bb * NN + i) * D + (lg << 3);
    float4 air00 = *reinterpret_cast<const float4*>(air_p);
    float4 air01 = *reinterpret_cast<const float4*>(air_p + 4);
    float4 air10 = *reinterpret_cast<const float4*>(air_p + 32);
    float4 air11 = *reinterpret_cast<const float4*>(air_p + 36);
    pin4(air00); pin4(air01); pin4(air10); pin4(air11);

    const float* aj_b = aj_g + (size_t)bb * NN * D;

    float m_run = 0.0f, l_run = 0.0f;
    float o[3][4];
#pragma unroll
    for (int mt = 0; mt < 3; ++mt)
#pragma unroll
        for (int r = 0; r < 4; ++r) o[mt][r] = 0.0f;

    // rolling load buffers (half-window pipeline)
    float4 qa0, qa1, qa2, qa3, qb0, qb1, qb2, qb3;
    auto ldq = [&](int jt, float4& d0, float4& d1, float4& d2, float4& d3) {
        const int jsrc = min(jt + lr, i);     // clamp: always a valid row
        const float* ajr = aj_b + (size_t)jsrc * D + (lg << 3);
        d0 = *reinterpret_cast<const float4*>(ajr);
        d1 = *reinterpret_cast<const float4*>(ajr + 4);
        d2 = *reinterpret_cast<const float4*>(ajr + 32);
        d3 = *reinterpret_cast<const float4*>(ajr + 36);
    };

    const int jb0 = w << 5;
    ldq(jb0, qa0, qa1, qa2, qa3);

    for (int jbase = jb0; jbase <= i; jbase += 128) {
        f32x4 acc[3][2];
#pragma unroll
        for (int mt = 0; mt < 3; ++mt)
#pragma unroll
            for (int n = 0; n < 2; ++n)
                acc[mt][n] = (f32x4){bv2[mt][0], bv2[mt][1], bv2[mt][2], bv2[mt][3]};

        // ---- n = 0 tile: issue n=1 loads, then gelu+MFMA on qa ----
        ldq(jbase + 16, qb0, qb1, qb2, qb3);
        {
            f16x8 B0 = frag8(air00, air01, qa0, qa1);
            f16x8 B1 = frag8(air10, air11, qa2, qa3);
#pragma unroll
            for (int mt = 0; mt < 3; ++mt) {
                acc[mt][0] = __builtin_amdgcn_mfma_f32_16x16x32_f16(
                    w2t[mt][0], B0, acc[mt][0], 0, 0, 0);
                acc[mt][0] = __builtin_amdgcn_mfma_f32_16x16x32_f16(
                    w2t[mt][1], B1, acc[mt][0], 0, 0, 0);
            }
        }
        // ---- n = 1 tile: issue next-window loads, then gelu+MFMA on qb ----
        ldq(jbase + 128, qa0, qa1, qa2, qa3);   // clamped-safe past end
        {
            f16x8 B0 = frag8(air00, air01, qb0, qb1);
            f16x8 B1 = frag8(air10, air11, qb2, qb3);
#pragma unroll
            for (int mt = 0; mt < 3; ++mt) {
                acc[mt][1] = __builtin_amdgcn_mfma_f32_16x16x32_f16(
                    w2t[mt][0], B0, acc[mt][1], 0, 0, 0);
                acc[mt][1] = __builtin_amdgcn_mfma_f32_16x16x32_f16(
                    w2t[mt][1], B1, acc[mt][1], 0, 0, 0);
            }
        }

        // ---- ||p|| per j (j on lr lanes), online softmax with defer-rescale ----
        float sv[2];
#pragma unroll
        for (int n = 0; n < 2; ++n) {
            float sq = 0.0f;
#pragma unroll
            for (int mt = 0; mt < 3; ++mt)
#pragma unroll
                for (int r = 0; r < 4; ++r)
                    sq = fmaf(acc[mt][n][r], acc[mt][n][r], sq);
            sq += __shfl_xor(sq, 16);
            sq += __shfl_xor(sq, 32);
            int j = jbase + n * 16 + lr;
            sv[n] = (j <= i) ? __builtin_amdgcn_sqrtf(sq) : -1e30f;
        }
        float mx = fmaxf(sv[0], sv[1]);
        mx = fmaxf(mx, __shfl_xor(mx, 1));
        mx = fmaxf(mx, __shfl_xor(mx, 2));
        mx = fmaxf(mx, __shfl_xor(mx, 4));
        mx = fmaxf(mx, __shfl_xor(mx, 8));
        if (mx > m_run) {                      // wave-uniform branch
            float scale = __expf(m_run - mx);
            l_run *= scale;
#pragma unroll
            for (int mt = 0; mt < 3; ++mt)
#pragma unroll
                for (int r = 0; r < 4; ++r) o[mt][r] *= scale;
            m_run = mx;
        }
        float w0 = __expf(sv[0] - m_run);      // masked j -> exactly 0
        float w1 = __expf(sv[1] - m_run);
        l_run += w0 + w1;
#pragma unroll
        for (int mt = 0; mt < 3; ++mt)
#pragma unroll
            for (int r = 0; r < 4; ++r)
                o[mt][r] = fmaf(w0, acc[mt][0][r], fmaf(w1, acc[mt][1][r], o[mt][r]));
    }

    // ---- reduce o over the 16 j-lanes, merge 4 waves ----
#pragma unroll
    for (int mt = 0; mt < 3; ++mt)
#pragma unroll
        for (int r = 0; r < 4; ++r) {
            float v = o[mt][r];
            v += __shfl_xor(v, 1);
            v += __shfl_xor(v, 2);
            v += __shfl_xor(v, 4);
            v += __shfl_xor(v, 8);
            o[mt][r] = v;
        }
    l_run += __shfl_xor(l_run, 1);
    l_run += __shfl_xor(l_run, 2);
    l_run += __shfl_xor(l_run, 4);
    l_run += __shfl_xor(l_run, 8);

    if (lr == 0) {
#pragma unroll
        for (int mt = 0; mt < 3; ++mt)
#pragma unroll
            for (int r = 0; r < 4; ++r) {
                int d = mt * 16 + lg * 4 + r;
                if (d < D) mbuf[w * 56 + d] = o[mt][r];
            }
        if (lg == 0) { mbuf[w * 56 + 48] = l_run; mbuf[w * 56 + 49] = m_run; }
    }
    __syncthreads();
    if (t < D) {
        float M = fmaxf(fmaxf(mbuf[49], mbuf[56 + 49]),
                        fmaxf(mbuf[112 + 49], mbuf[168 + 49]));
        float L = 0.0f, val = 0.0f;
#pragma unroll
        for (int ww = 0; ww < 4; ++ww) {
            float c = __expf(mbuf[ww * 56 + 49] - M);
            L = fmaf(c, mbuf[ww * 56 + 48], L);
            val = fmaf(c, mbuf[ww * 56 + t], val);
        }
        out[((size_t)bb * NN + i) * D + t] = val / L;
    }
}

extern "C" void kernel_launch(void* const* d_in, const int* in_sizes, int n_in,
                              void* d_out, int out_size, void* d_ws, size_t ws_size,
                              hipStream_t stream) {
    const float* x  = (const float*)d_in[0];
    const float* W1 = (const float*)d_in[1];
    const float* b1 = (const float*)d_in[2];
    const float* W2 = (const float*)d_in[3];
    const float* b2 = (const float*)d_in[4];
    float* out = (float*)d_out;

    float* ai = (float*)d_ws;                          // B*N*D floats
    float* aj = ai + (size_t)BB * NN * D;              // B*N*D floats
    uint4* w2fT = (uint4*)(aj + (size_t)BB * NN * D);  // 6*64 uint4 (also OOB pad)

    precompute_kernel<<<BB * NN, 64, 0, stream>>>(x, W1, b1, W2, ai, aj, w2fT);
    pair_kernel<<<BB * NN, 256, 0, stream>>>(ai, aj, w2fT, b2, out);
}

// Round 9
// 35.169 us; speedup vs baseline: 1.1994x; 1.1994x over previous
//
#include <hip/hip_runtime.h>
#include <math.h>

#define D 40
#define NN 1024
#define BB 2

typedef __attribute__((ext_vector_type(8))) _Float16 f16x8;
typedef __attribute__((ext_vector_type(4))) float f32x4;

__device__ __forceinline__ unsigned int pk16(float a, float b) {
    return __builtin_bit_cast(unsigned int, __builtin_amdgcn_cvt_pkrtz(a, b));
}

// gelu = a - a/(exp2(a*(c1*a^2+c0))+1); 5 VALU + 2 trans
__device__ __forceinline__ float gelu_tanh(float a) {
    float u = a * a;
    float t1 = fmaf(0.10294366f, u, 2.3022083f);
    float e = __builtin_amdgcn_exp2f(a * t1);
    float r = __builtin_amdgcn_rcpf(e + 1.0f);
    return fmaf(-a, r, a);
}

// anti-remat pins
__device__ __forceinline__ void pinf(float& x) { asm volatile("" : "+v"(x)); }
__device__ __forceinline__ void pin4(float4& v) {
    asm volatile("" : "+v"(v.x), "+v"(v.y), "+v"(v.z), "+v"(v.w));
}
__device__ __forceinline__ void pin8(f16x8& v) {
    uint4 u = __builtin_bit_cast(uint4, v);
    asm volatile("" : "+v"(u.x), "+v"(u.y), "+v"(u.z), "+v"(u.w));
    v = __builtin_bit_cast(f16x8, u);
}

// build fp16x8 B-fragment: gelu(air + ajv) for 8 consecutive k
__device__ __forceinline__ f16x8 frag8(float4 a0, float4 a1, float4 x0, float4 x1) {
    float g0 = gelu_tanh(a0.x + x0.x);
    float g1 = gelu_tanh(a0.y + x0.y);
    float g2 = gelu_tanh(a0.z + x0.z);
    float g3 = gelu_tanh(a0.w + x0.w);
    float g4 = gelu_tanh(a1.x + x1.x);
    float g5 = gelu_tanh(a1.y + x1.y);
    float g6 = gelu_tanh(a1.z + x1.z);
    float g7 = gelu_tanh(a1.w + x1.w);
    return __builtin_bit_cast(f16x8,
        make_uint4(pk16(g0, g1), pk16(g2, g3), pk16(g4, g5), pk16(g6, g7)));
}

// ai = x @ W1[:D] + b1, aj = x @ W1[D:]; block 0 packs W2^T fp16 A-fragments
__global__ __launch_bounds__(64) void precompute_kernel(
    const float* __restrict__ x, const float* __restrict__ W1,
    const float* __restrict__ b1, const float* __restrict__ W2,
    float* __restrict__ ai, float* __restrict__ aj, uint4* __restrict__ w2fT) {
    int r = blockIdx.x;
    int t = threadIdx.x;
    __shared__ float xr[D];
    if (t < D) xr[t] = x[(size_t)r * D + t];
    __syncthreads();
    if (t < D) {
        float s1 = b1[t];
        float s2 = 0.0f;
#pragma unroll
        for (int k = 0; k < D; ++k) {
            float xv = xr[k];
            s1 = fmaf(xv, W1[k * D + t], s1);
            s2 = fmaf(xv, W1[(D + k) * D + t], s2);
        }
        ai[(size_t)r * D + t] = s1;
        aj[(size_t)r * D + t] = s2;
    }
    if (r == 0) {
        // A = W2^T: A[m=d, k] = W2[k][d]; lane: m = l&15, k = kt*32 + (l>>4)*8 + e
        const int lr = t & 15, lg = t >> 4;
#pragma unroll
        for (int mt = 0; mt < 3; ++mt)
#pragma unroll
            for (int kt = 0; kt < 2; ++kt) {
                unsigned int u[4];
#pragma unroll
                for (int pe = 0; pe < 4; ++pe) {
                    int k0 = kt * 32 + lg * 8 + pe * 2;
                    int dd = mt * 16 + lr;
                    float v0 = (k0 < D && dd < D) ? W2[k0 * D + dd] : 0.0f;
                    float v1 = (k0 + 1 < D && dd < D) ? W2[(k0 + 1) * D + dd] : 0.0f;
                    u[pe] = pk16(v0, v1);
                }
                w2fT[(mt * 2 + kt) * 64 + t] = make_uint4(u[0], u[1], u[2], u[3]);
            }
    }
}

__global__ __launch_bounds__(256)
__attribute__((amdgpu_waves_per_eu(4)))     // min 4 waves/EU -> VGPR budget <= 128
void pair_kernel(
    const float* __restrict__ ai_g, const float* __restrict__ aj_g,
    const uint4* __restrict__ w2fT, const float* __restrict__ b2,
    float* __restrict__ out) {
    __shared__ float mbuf[224];               // 4 waves x 56 (only LDS use)

    const int t = threadIdx.x;
    const int bid = blockIdx.x;
    const int bb = bid & 1;
    const int i = NN - 1 - (bid >> 1);        // big rows first
    const int w = t >> 6;
    const int l = t & 63;
    const int lr = l & 15;
    const int lg = l >> 4;                    // 0..3: k-group of this lane's fragments
    const int jlo = l & 31;                   // phase-B j owner
    const int kk = (l >> 5) << 2;             // phase-B k sub-block: 0 or 4

    // W2^T A-fragments (zero rows for k>=40 kill don't-care B slots), pinned
    f16x8 w2t[3][2];
#pragma unroll
    for (int mt = 0; mt < 3; ++mt)
#pragma unroll
        for (int kt = 0; kt < 2; ++kt) {
            w2t[mt][kt] = __builtin_bit_cast(f16x8, w2fT[(mt * 2 + kt) * 64 + l]);
            pin8(w2t[mt][kt]);
        }

    // bias for d = mt*16 + lg*4 + r (0 for d >= 40), pinned
    float bv2[3][4];
#pragma unroll
    for (int mt = 0; mt < 3; ++mt)
#pragma unroll
        for (int r = 0; r < 4; ++r) {
            int d = mt * 16 + lg * 4 + r;
            bv2[mt][r] = (d < D) ? b2[d] : 0.0f;
            pinf(bv2[mt][r]);
        }

    const float* ai_row = ai_g + ((size_t)bb * NN + i) * D;
    // phase-A ai: k = lg*8 .. lg*8+7  (all useful, k<32)
    float4 air0 = *reinterpret_cast<const float4*>(ai_row + (lg << 3));
    float4 air1 = *reinterpret_cast<const float4*>(ai_row + (lg << 3) + 4);
    // phase-B ai: k = 32+kk .. 32+kk+3
    float4 ai32 = *reinterpret_cast<const float4*>(ai_row + 32 + kk);
    pin4(air0); pin4(air1); pin4(ai32);

    const float* aj_b = aj_g + (size_t)bb * NN * D;

    float m_run = 0.0f, l_run = 0.0f;
    float o[3][4];
#pragma unroll
    for (int mt = 0; mt < 3; ++mt)
#pragma unroll
        for (int r = 0; r < 4; ++r) o[mt][r] = 0.0f;

    for (int jbase = w << 5; jbase <= i; jbase += 128) {
        // ---- loads: phase A (2 n-tiles x 2 float4) + phase B (1 float4) ----
        float4 qa0, qa1, qb0, qb1, qt;
        {
            const int j0 = min(jbase + lr, i);
            const float* r0 = aj_b + (size_t)j0 * D + (lg << 3);
            qa0 = *reinterpret_cast<const float4*>(r0);
            qa1 = *reinterpret_cast<const float4*>(r0 + 4);
            const int j1 = min(jbase + 16 + lr, i);
            const float* r1 = aj_b + (size_t)j1 * D + (lg << 3);
            qb0 = *reinterpret_cast<const float4*>(r1);
            qb1 = *reinterpret_cast<const float4*>(r1 + 4);
            const int jt = min(jbase + jlo, i);
            qt = *reinterpret_cast<const float4*>(aj_b + (size_t)jt * D + 32 + kk);
        }

        // ---- phase B: 4 tail gelu (k=32+kk..+3) for j=jbase+jlo, then bpermute ----
        unsigned int pd0, pd1;
        {
            float g0 = gelu_tanh(ai32.x + qt.x);
            float g1 = gelu_tanh(ai32.y + qt.y);
            float g2 = gelu_tanh(ai32.z + qt.z);
            float g3 = gelu_tanh(ai32.w + qt.w);
            pd0 = pk16(g0, g1);                // kpairs (32+kk, 33+kk)
            pd1 = pk16(g2, g3);                // kpairs (34+kk, 35+kk)
        }
        // kt=1 frag for n-tile n: dwords = k-pairs (32,33),(34,35),(36,37),(38,39)
        // from src lanes (16n+lr) [kk=0] and (16n+lr+32) [kk=4]
        const int idx0 = lr << 2;              // n=0 base byte index
        uint4 tB0, tB1;
        tB0.x = __builtin_amdgcn_ds_bpermute(idx0,       pd0);
        tB0.y = __builtin_amdgcn_ds_bpermute(idx0,       pd1);
        tB0.z = __builtin_amdgcn_ds_bpermute(idx0 + 128, pd0);
        tB0.w = __builtin_amdgcn_ds_bpermute(idx0 + 128, pd1);
        tB1.x = __builtin_amdgcn_ds_bpermute(idx0 + 64,  pd0);
        tB1.y = __builtin_amdgcn_ds_bpermute(idx0 + 64,  pd1);
        tB1.z = __builtin_amdgcn_ds_bpermute(idx0 + 192, pd0);
        tB1.w = __builtin_amdgcn_ds_bpermute(idx0 + 192, pd1);

        // ---- MFMA ----
        f32x4 acc[3][2];
#pragma unroll
        for (int mt = 0; mt < 3; ++mt)
#pragma unroll
            for (int n = 0; n < 2; ++n)
                acc[mt][n] = (f32x4){bv2[mt][0], bv2[mt][1], bv2[mt][2], bv2[mt][3]};

        {
            f16x8 B = frag8(air0, air1, qa0, qa1);
            f16x8 Bt = __builtin_bit_cast(f16x8, tB0);
#pragma unroll
            for (int mt = 0; mt < 3; ++mt) {
                acc[mt][0] = __builtin_amdgcn_mfma_f32_16x16x32_f16(
                    w2t[mt][0], B, acc[mt][0], 0, 0, 0);
                acc[mt][0] = __builtin_amdgcn_mfma_f32_16x16x32_f16(
                    w2t[mt][1], Bt, acc[mt][0], 0, 0, 0);
            }
        }
        {
            f16x8 B = frag8(air0, air1, qb0, qb1);
            f16x8 Bt = __builtin_bit_cast(f16x8, tB1);
#pragma unroll
            for (int mt = 0; mt < 3; ++mt) {
                acc[mt][1] = __builtin_amdgcn_mfma_f32_16x16x32_f16(
                    w2t[mt][0], B, acc[mt][1], 0, 0, 0);
                acc[mt][1] = __builtin_amdgcn_mfma_f32_16x16x32_f16(
                    w2t[mt][1], Bt, acc[mt][1], 0, 0, 0);
            }
        }

        // ---- ||p|| per j (j on lr lanes), online softmax with defer-rescale ----
        float sv[2];
#pragma unroll
        for (int n = 0; n < 2; ++n) {
            float sq = 0.0f;
#pragma unroll
            for (int mt = 0; mt < 3; ++mt)
#pragma unroll
                for (int r = 0; r < 4; ++r)
                    sq = fmaf(acc[mt][n][r], acc[mt][n][r], sq);
            sq += __shfl_xor(sq, 16);
            sq += __shfl_xor(sq, 32);
            int j = jbase + n * 16 + lr;
            sv[n] = (j <= i) ? __builtin_amdgcn_sqrtf(sq) : -1e30f;
        }
        float mx = fmaxf(sv[0], sv[1]);
        mx = fmaxf(mx, __shfl_xor(mx, 1));
        mx = fmaxf(mx, __shfl_xor(mx, 2));
        mx = fmaxf(mx, __shfl_xor(mx, 4));
        mx = fmaxf(mx, __shfl_xor(mx, 8));
        if (mx > m_run) {                      // wave-uniform branch
            float scale = __expf(m_run - mx);
            l_run *= scale;
#pragma unroll
            for (int mt = 0; mt < 3; ++mt)
#pragma unroll
                for (int r = 0; r < 4; ++r) o[mt][r] *= scale;
            m_run = mx;
        }
        float w0 = __expf(sv[0] - m_run);      // masked j -> exactly 0
        float w1 = __expf(sv[1] - m_run);
        l_run += w0 + w1;
#pragma unroll
        for (int mt = 0; mt < 3; ++mt)
#pragma unroll
            for (int r = 0; r < 4; ++r)
                o[mt][r] = fmaf(w0, acc[mt][0][r], fmaf(w1, acc[mt][1][r], o[mt][r]));
    }

    // ---- reduce o over the 16 j-lanes, merge 4 waves ----
#pragma unroll
    for (int mt = 0; mt < 3; ++mt)
#pragma unroll
        for (int r = 0; r < 4; ++r) {
            float v = o[mt][r];
            v += __shfl_xor(v, 1);
            v += __shfl_xor(v, 2);
            v += __shfl_xor(v, 4);
            v += __shfl_xor(v, 8);
            o[mt][r] = v;
        }
    l_run += __shfl_xor(l_run, 1);
    l_run += __shfl_xor(l_run, 2);
    l_run += __shfl_xor(l_run, 4);
    l_run += __shfl_xor(l_run, 8);

    if (lr == 0) {
#pragma unroll
        for (int mt = 0; mt < 3; ++mt)
#pragma unroll
            for (int r = 0; r < 4; ++r) {
                int d = mt * 16 + lg * 4 + r;
                if (d < D) mbuf[w * 56 + d] = o[mt][r];
            }
        if (lg == 0) { mbuf[w * 56 + 48] = l_run; mbuf[w * 56 + 49] = m_run; }
    }
    __syncthreads();
    if (t < D) {
        float M = fmaxf(fmaxf(mbuf[49], mbuf[56 + 49]),
                        fmaxf(mbuf[112 + 49], mbuf[168 + 49]));
        float L = 0.0f, val = 0.0f;
#pragma unroll
        for (int ww = 0; ww < 4; ++ww) {
            float c = __expf(mbuf[ww * 56 + 49] - M);
            L = fmaf(c, mbuf[ww * 56 + 48], L);
            val = fmaf(c, mbuf[ww * 56 + t], val);
        }
        out[((size_t)bb * NN + i) * D + t] = val / L;
    }
}

extern "C" void kernel_launch(void* const* d_in, const int* in_sizes, int n_in,
                              void* d_out, int out_size, void* d_ws, size_t ws_size,
                              hipStream_t stream) {
    const float* x  = (const float*)d_in[0];
    const float* W1 = (const float*)d_in[1];
    const float* b1 = (const float*)d_in[2];
    const float* W2 = (const float*)d_in[3];
    const float* b2 = (const float*)d_in[4];
    float* out = (float*)d_out;

    float* ai = (float*)d_ws;                          // B*N*D floats
    float* aj = ai + (size_t)BB * NN * D;              // B*N*D floats
    uint4* w2fT = (uint4*)(aj + (size_t)BB * NN * D);  // 6*64 uint4

    precompute_kernel<<<BB * NN, 64, 0, stream>>>(x, W1, b1, W2, ai, aj, w2fT);
    pair_kernel<<<BB * NN, 256, 0, stream>>>(ai, aj, w2fT, b2, out);
}